// Round 2
// baseline (347.373 us; speedup 1.0000x reference)
//
#include <hip/hip_runtime.h>

// Problem constants (fixed by the reference):
//   B=8, HEADS=8, N=3136, D=32, K2=9
constexpr int Bc   = 8;
constexpr int Hh   = 8;
constexpr int Nn   = 3136;
constexpr int Dd   = 32;
constexpr int K2c  = 9;
constexpr int ROWS = Bc * Hh * Nn;          // 200704 flattened (b,h,n) rows
constexpr int RPB  = 8;                     // rows per block (N % 8 == 0 -> h,b uniform)
constexpr int BLOCK = 256;
constexpr int VROW = Dd * K2c;              // 288 floats per v row
constexpr int VBLK = RPB * VROW;            // 2304 floats = 576 float4 per block

__global__ __launch_bounds__(BLOCK, 8)
void swattn_av_kernel(const float* __restrict__ q,          // [B,H,N,D]
                      const float* __restrict__ attn_local, // [B,H,N,K2]
                      const float* __restrict__ v,          // [B,H,N,D,K2]
                      const float* __restrict__ tok,        // [H,D,K2]
                      const float* __restrict__ bias,       // [H,N,K2]
                      float* __restrict__ out) {            // [B,H,N,D]
    __shared__ float T_lds[VROW];                   // 288 floats, this block's head
    __shared__ float q_lds[RPB][Dd + 1];            // +1 pad -> conflict-free col reads
    __shared__ float attn_lds[RPB][K2c];            // 8 x 9 attn weights
    __shared__ float v_lds[VBLK];                   // 2304 floats (9216 B), this block's v

    const int tid  = threadIdx.x;
    const int base = blockIdx.x * RPB;              // first global row of this block
    const int h    = (base / Nn) % Hh;              // uniform across the block
    const int lrow = tid >> 5, d = tid & 31;

    // --- Phase 0: issue EVERY global load up front (max memory-level parallelism) ---
    // v: 576 float4, perfectly coalesced 16B/lane streaming (the 6.3 TB/s pattern)
    const float4* __restrict__ vsrc =
        reinterpret_cast<const float4*>(v + (size_t)base * VROW);
    float4* vdst = reinterpret_cast<float4*>(v_lds);
    float4 vv0 = vsrc[tid];
    float4 vv1 = vsrc[tid + 256];
    float4 vv2 = make_float4(0.f, 0.f, 0.f, 0.f);
    if (tid < VBLK / 4 - 512)                       // threads 0..63 take the tail
        vv2 = vsrc[tid + 512];

    // tok: 72 float4 (1152 B), coalesced, L2-resident
    float4 tt = make_float4(0.f, 0.f, 0.f, 0.f);
    if (tid < VROW / 4)
        tt = reinterpret_cast<const float4*>(tok + h * VROW)[tid];

    // q: 256 dwords, coalesced
    const float qv = q[(base + lrow) * Dd + d];

    // attn_local + bias for the 72 phase-A lanes -> registers (off the critical path)
    float al = 0.f, bs = 0.f;
    int arow = 0, ak = 0;
    if (tid < RPB * K2c) {
        arow = tid / K2c;
        ak   = tid - arow * K2c;
        const int gr = base + arow;
        al = attn_local[gr * K2c + ak];
        bs = bias[(gr % (Hh * Nn)) * K2c + ak];     // (h*N + n)*K2 + k
    }

    // commit staged data to LDS
    vdst[tid]       = vv0;
    vdst[tid + 256] = vv1;
    if (tid < VBLK / 4 - 512)
        vdst[tid + 512] = vv2;
    if (tid < VROW / 4)
        reinterpret_cast<float4*>(T_lds)[tid] = tt;
    q_lds[lrow][d] = qv;
    __syncthreads();

    // --- Phase A: 72 threads compute attn[arow][ak] = q . T_k + bias + local ---
    if (tid < RPB * K2c) {
        float s0 = 0.f, s1 = 0.f, s2 = 0.f, s3 = 0.f;
        #pragma unroll
        for (int dd = 0; dd < Dd; dd += 4) {
            s0 += q_lds[arow][dd + 0] * T_lds[(dd + 0) * K2c + ak];
            s1 += q_lds[arow][dd + 1] * T_lds[(dd + 1) * K2c + ak];
            s2 += q_lds[arow][dd + 2] * T_lds[(dd + 2) * K2c + ak];
            s3 += q_lds[arow][dd + 3] * T_lds[(dd + 3) * K2c + ak];
        }
        attn_lds[arow][ak] = ((s0 + s1) + (s2 + s3)) + al + bs;
    }
    __syncthreads();

    // --- Phase B: 256 threads, one output each: out[gr][d] = attn . v_row(d,:) ---
    // v_lds index = lrow*288 + 9*d + k; 288 % 32 == 0 and gcd(9,32)==1 ->
    // the 32 d-lanes hit all 32 banks, 2 lrows/bank = free 2-way aliasing.
    {
        float a[K2c];
        #pragma unroll
        for (int k = 0; k < K2c; ++k)
            a[k] = attn_lds[lrow][k];
        const float* __restrict__ vr = v_lds + lrow * VROW + d * K2c;
        float acc = 0.f;
        #pragma unroll
        for (int k = 0; k < K2c; ++k)
            acc += a[k] * vr[k];
        out[(base + lrow) * Dd + d] = acc;
    }
}

extern "C" void kernel_launch(void* const* d_in, const int* in_sizes, int n_in,
                              void* d_out, int out_size, void* d_ws, size_t ws_size,
                              hipStream_t stream) {
    const float* q          = (const float*)d_in[0];   // q_norm          [B,H,N,D]
    const float* attn_local = (const float*)d_in[1];   // attn_local      [B,H,N,K2]
    const float* v          = (const float*)d_in[2];   // v_local         [B,H,N,D,K2]
    const float* tok        = (const float*)d_in[3];   // learnable_tokens[H,D,K2]
    const float* bias       = (const float*)d_in[4];   // learnable_bias  [H,N,K2]
    // d_in[5..7] = window_size, H, W scalars (unused; K2=9 baked in)
    float* out = (float*)d_out;

    const int grid = ROWS / RPB;                       // 25088, exact
    swattn_av_kernel<<<grid, BLOCK, 0, stream>>>(q, attn_local, v, tok, bias, out);
}